// Round 4
// baseline (388.216 us; speedup 1.0000x reference)
//
#include <hip/hip_runtime.h>
#include <hip/hip_cooperative_groups.h>

namespace cg = cooperative_groups;

// ---------------------------------------------------------------------------
// PASingleRoIExtractor: RoIAlign(out=7, sn=2) on 4 FPN levels + max-combine.
// ONE cooperative kernel:
//   phase 1: grid-stride NCHW fp32 -> NHWC f16 transpose (LDS [x][c] tiles)
//   grid.sync()
//   phase 2: grid-stride roi blocks (4/roi, 64 ch each), v_dot2_f32_f16 inner.
// Fallbacks: split kernels if coop launch fails; direct NCHW if ws too small.
// ---------------------------------------------------------------------------

#define NCH 256
#define NBIN 49
#define NTILE 5504

typedef _Float16 half2v __attribute__((ext_vector_type(2)));

#if defined(__has_builtin)
#if __has_builtin(__builtin_amdgcn_fdot2)
#define HAVE_FDOT2 1
#endif
#if __has_builtin(__builtin_amdgcn_cvt_pkrtz)
#define HAVE_PKRTZ 1
#endif
#endif

__device__ __constant__ int    d_H[4]      = {256, 128, 64, 32};
__device__ __constant__ float  d_scale[4]  = {0.25f, 0.125f, 0.0625f, 0.03125f};
__device__ __constant__ int    d_off4[4]   = {0, 2097152, 2621440, 2752512};    // uint4 units
__device__ __constant__ size_t d_offu[4]   = {0, 16777216, 20971520, 22020096}; // f16 units
__device__ __constant__ int    d_tstart[4] = {0, 4096, 5120, 5376};
__device__ __constant__ int    d_tilesx[4] = {4, 2, 1, 1};
__device__ __constant__ int    d_tshift[4] = {2, 1, 0, 0};
__device__ __constant__ int    d_hshift[4] = {8, 7, 6, 5};

__device__ __forceinline__ int pack_h2(float a, float b) {
#ifdef HAVE_PKRTZ
    return __builtin_bit_cast(int, __builtin_amdgcn_cvt_pkrtz(a, b));
#else
    half2v h;
    h.x = (_Float16)a;
    h.y = (_Float16)b;
    return __builtin_bit_cast(int, h);
#endif
}
__device__ __forceinline__ half2v bc_h2(int x) { return __builtin_bit_cast(half2v, x); }
__device__ __forceinline__ half2v bc_h2u(unsigned x) { return __builtin_bit_cast(half2v, x); }

#ifdef HAVE_FDOT2
#define ACC2(uLLc, uLHc, w2, k0)                                                                       \
    acc[k0] = __builtin_amdgcn_fdot2(bc_h2u(__builtin_amdgcn_perm((uLHc), (uLLc), 0x05040100u)), (w2), \
                                     acc[k0], false);                                                  \
    acc[k0 + 1] = __builtin_amdgcn_fdot2(                                                              \
        bc_h2u(__builtin_amdgcn_perm((uLHc), (uLLc), 0x07060302u)), (w2), acc[k0 + 1], false)
#else
#define ACC2(uLLc, uLHc, w2, k0)                                       \
    do {                                                               \
        half2v a_ = bc_h2u(uLLc), b_ = bc_h2u(uLHc);                   \
        float w0_ = (float)(w2).x, w1_ = (float)(w2).y;                \
        acc[k0]     = fmaf((float)a_.x, w0_, acc[k0]);                 \
        acc[k0]     = fmaf((float)b_.x, w1_, acc[k0]);                 \
        acc[k0 + 1] = fmaf((float)a_.y, w0_, acc[k0 + 1]);             \
        acc[k0 + 1] = fmaf((float)b_.y, w1_, acc[k0 + 1]);             \
    } while (0)
#endif

__device__ __forceinline__ void do_sample(const uint4* __restrict__ base, float* acc, int4 ye,
                                          int4 xe) {
    uint4 uLL = base[ye.x + xe.x];
    uint4 uLH = base[ye.x + xe.y];
    uint4 uHL = base[ye.y + xe.x];
    uint4 uHH = base[ye.y + xe.y];
    half2v wx = bc_h2(xe.z);
    half2v wlo = bc_h2(ye.z) * wx;  // {wyl*wxl, wyl*wxh}
    half2v whi = bc_h2(ye.w) * wx;  // {wyh*wxl, wyh*wxh}
    ACC2(uLL.x, uLH.x, wlo, 0);
    ACC2(uLL.y, uLH.y, wlo, 2);
    ACC2(uLL.z, uLH.z, wlo, 4);
    ACC2(uLL.w, uLH.w, wlo, 6);
    ACC2(uHL.x, uHH.x, whi, 0);
    ACC2(uHL.y, uHH.y, whi, 2);
    ACC2(uHL.z, uHH.z, whi, 4);
    ACC2(uHL.w, uHH.w, whi, 6);
}

// ---------------------------------------------------------------------------
// One transpose tile: 64 x-pixels x 64 channels of one (level, y) row.
// LDS layout [x][c], stride 65: global float2 reads (coalesced), LDS reads
// on the pack side are contiguous 8-float runs (2-way banks = free).
// Ends with __syncthreads so the tile buffer can be reused.
// ---------------------------------------------------------------------------
__device__ __forceinline__ void transpose_tile(int t, const float* __restrict__ f0,
                                               const float* __restrict__ f1,
                                               const float* __restrict__ f2,
                                               const float* __restrict__ f3,
                                               unsigned short* __restrict__ out, float* tile,
                                               int tid) {
    const int lvl = (t >= d_tstart[1]) + (t >= d_tstart[2]) + (t >= d_tstart[3]);
    int rem = t - d_tstart[lvl];
    const int H = d_H[lvl];
    const int xt = rem & (d_tilesx[lvl] - 1);
    rem >>= d_tshift[lvl];
    const int y = rem & (H - 1);
    const int cgi = rem >> d_hshift[lvl];
    const int x0 = xt * 64;
    const float* in = (lvl == 0) ? f0 : (lvl == 1) ? f1 : (lvl == 2) ? f2 : f3;
    unsigned short* o = out + d_offu[lvl];

    const int tx2 = tid & 31, wv = tid >> 5;
    const size_t HW = (size_t)H * H;
    const float* inp = in + (size_t)(cgi * 64) * HW + (size_t)y * H + x0;
    const bool xin = (x0 + 2 * tx2) < H;
#pragma unroll
    for (int r = 0; r < 8; ++r) {
        int cl = wv * 8 + r;
        float2 v = make_float2(0.0f, 0.0f);
        if (xin) v = *(const float2*)(inp + (size_t)cl * HW + 2 * tx2);
        tile[(2 * tx2) * 65 + cl] = v.x;
        tile[(2 * tx2 + 1) * 65 + cl] = v.y;
    }
    __syncthreads();
    const int o8 = tid & 7, xi = tid >> 3;
#pragma unroll
    for (int pass = 0; pass < 2; ++pass) {
        int px = xi + pass * 32;
        int x = x0 + px;
        if (x < H) {
            const float* col = &tile[px * 65 + o8 * 8];
            unsigned d0 = (unsigned)pack_h2(col[0], col[1]);
            unsigned d1 = (unsigned)pack_h2(col[2], col[3]);
            unsigned d2 = (unsigned)pack_h2(col[4], col[5]);
            unsigned d3 = (unsigned)pack_h2(col[6], col[7]);
            *(uint4*)(o + (size_t)(y * H + x) * NCH + cgi * 64 + o8 * 8) =
                make_uint4(d0, d1, d2, d3);
        }
    }
    __syncthreads();
}

// ---------------------------------------------------------------------------
// One roi quarter-block: 64 channels of roi n. Caller provides LDS regions.
// Caller must __syncthreads before entry (LDS reuse).
// ---------------------------------------------------------------------------
__device__ __forceinline__ void roi_block(int vb, const uint4* __restrict__ ws,
                                          const float* __restrict__ rois,
                                          float* __restrict__ out, float* smem, int4* tbl,
                                          int tid) {
    const int n = vb >> 2;
    const int quarter = vb & 3;
    const float* r = rois + (size_t)n * 5;

    if (tid < 112) {
        int lvl = tid / 28;
        int e = tid % 28;
        int axis = e / 14;  // 0 = y, 1 = x
        int s = e % 14;
        int H = d_H[lvl];
        float sc = d_scale[lvl];
        float a = (axis ? r[1] : r[2]) * sc;
        float b2 = (axis ? r[3] : r[4]) * sc;
        float binsz = fmaxf(b2 - a, 1.0f) * (1.0f / 7.0f);
        float g = (float)(s >> 1) + 0.25f + 0.5f * (float)(s & 1);
        float coord = a + g * binsz;
        float valid = (coord > -1.0f && coord < (float)H) ? 1.0f : 0.0f;
        float c = fminf(fmaxf(coord, 0.0f), (float)H - 1.0f);
        int lo = (int)floorf(c);
        int hi = min(lo + 1, H - 1);
        float whi = (c - (float)lo) * valid;
        float wlo = (1.0f - (c - (float)lo)) * valid;
        int mult = axis ? 32 : H * 32;  // uint4 units: pixel = 32 uint4
        int4 tt;
        tt.x = lo * mult;
        tt.y = hi * mult;
        if (axis) {
            tt.z = pack_h2(wlo, whi);
            tt.w = 0;
        } else {
            tt.z = pack_h2(wlo, wlo);
            tt.w = pack_h2(whi, whi);
        }
        tbl[tid] = tt;  // [lvl*28 + axis*14 + s]
    }
    __syncthreads();

    const int p = tid & 7;
    const int h = tid >> 3;
    const int octet = quarter * 8 + p;
    const int bstart = (h * NBIN) >> 5;
    const int bend = ((h + 1) * NBIN) >> 5;

    for (int b = bstart; b < bend; ++b) {
        int by = b / 7;
        int bx = b - by * 7;
        float m[8];
#pragma unroll
        for (int k = 0; k < 8; ++k) m[k] = -3.402823e38f;
#pragma unroll
        for (int lvl = 0; lvl < 4; ++lvl) {
            const uint4* base = ws + d_off4[lvl] + octet;
            int4 ye0 = tbl[lvl * 28 + 2 * by];
            int4 ye1 = tbl[lvl * 28 + 2 * by + 1];
            int4 xe0 = tbl[lvl * 28 + 14 + 2 * bx];
            int4 xe1 = tbl[lvl * 28 + 14 + 2 * bx + 1];
            float acc[8];
#pragma unroll
            for (int k = 0; k < 8; ++k) acc[k] = 0.0f;
            do_sample(base, acc, ye0, xe0);
            do_sample(base, acc, ye0, xe1);
            do_sample(base, acc, ye1, xe0);
            do_sample(base, acc, ye1, xe1);
#pragma unroll
            for (int k = 0; k < 8; ++k) m[k] = fmaxf(m[k], acc[k] * 0.25f);
        }
#pragma unroll
        for (int k = 0; k < 8; ++k) smem[(p * 8 + k) * NBIN + b] = m[k];
    }
    __syncthreads();

    float4* o4 = (float4*)(out + (size_t)n * (NCH * NBIN) + (size_t)quarter * (64 * NBIN));
    const float4* s4 = (const float4*)smem;
    for (int i = tid; i < 64 * NBIN / 4; i += 256) o4[i] = s4[i];
}

// ---------------------------------------------------------------------------
// Cooperative mega-kernel: transpose phase -> grid.sync -> roi phase.
// LDS: 64*65 floats (16640 B) shared between phases.
// ---------------------------------------------------------------------------
__global__ __launch_bounds__(256, 8) void roi_mega(
    const float* __restrict__ f0, const float* __restrict__ f1, const float* __restrict__ f2,
    const float* __restrict__ f3, const float* __restrict__ rois, float* __restrict__ out,
    unsigned short* __restrict__ wsp, int nrois) {
    __shared__ float sh[64 * 65];
    const int tid = threadIdx.x;
    const int G = gridDim.x;

    for (int t = blockIdx.x; t < NTILE; t += G)
        transpose_tile(t, f0, f1, f2, f3, wsp, sh, tid);

    cg::this_grid().sync();

    const uint4* ws4 = (const uint4*)wsp;
    float* smem = sh;
    int4* tbl = (int4*)(sh + 64 * NBIN);  // byte 12544, 16B aligned
    const int nvb = 4 * nrois;
    for (int vb = blockIdx.x; vb < nvb; vb += G) {
        __syncthreads();
        roi_block(vb, ws4, rois, out, smem, tbl, tid);
    }
}

// ---------------------------------------------------------------------------
// Split-kernel fallback (same device code, two dispatches).
// ---------------------------------------------------------------------------
__global__ __launch_bounds__(256, 8) void transpose_k(
    const float* __restrict__ f0, const float* __restrict__ f1, const float* __restrict__ f2,
    const float* __restrict__ f3, unsigned short* __restrict__ wsp) {
    __shared__ float sh[64 * 65];
    const int tid = threadIdx.x;
    for (int t = blockIdx.x; t < NTILE; t += gridDim.x)
        transpose_tile(t, f0, f1, f2, f3, wsp, sh, tid);
}

__global__ __launch_bounds__(256, 8) void roi_k(const uint4* __restrict__ ws,
                                                const float* __restrict__ rois,
                                                float* __restrict__ out, int nrois) {
    __shared__ float sh[64 * 65];
    const int tid = threadIdx.x;
    float* smem = sh;
    int4* tbl = (int4*)(sh + 64 * NBIN);
    const int nvb = 4 * nrois;
    for (int vb = blockIdx.x; vb < nvb; vb += gridDim.x) {
        __syncthreads();
        roi_block(vb, ws, rois, out, smem, tbl, tid);
    }
}

// ---------------------------------------------------------------------------
// Fallback: direct NCHW fp32 gather (only if ws too small).
// ---------------------------------------------------------------------------
__device__ __forceinline__ int4 make_entry_f(float coord, int size, int mult) {
    float valid = (coord > -1.0f && coord < (float)size) ? 1.0f : 0.0f;
    float c = fminf(fmaxf(coord, 0.0f), (float)size - 1.0f);
    int lo = (int)floorf(c);
    int hi = min(lo + 1, size - 1);
    float whi = (c - (float)lo) * valid;
    float wlo = (1.0f - (c - (float)lo)) * valid;
    int4 r;
    r.x = lo * mult;
    r.y = hi * mult;
    r.z = __float_as_int(wlo);
    r.w = __float_as_int(whi);
    return r;
}

__global__ __launch_bounds__(256) void roi_direct(
    const float* __restrict__ f0, const float* __restrict__ f1, const float* __restrict__ f2,
    const float* __restrict__ f3, const float* __restrict__ rois, float* __restrict__ out) {
    const int n = blockIdx.x;
    const int c = threadIdx.x;
    const float* feats[4] = {f0, f1, f2, f3};
    const float* r = rois + (size_t)n * 5;
    for (int b = 0; b < NBIN; ++b) {
        int by = b / 7;
        int bx = b - by * 7;
        float m = -3.402823e38f;
#pragma unroll
        for (int lvl = 0; lvl < 4; ++lvl) {
            int H = d_H[lvl];
            float sc = d_scale[lvl];
            float x1 = r[1] * sc, y1 = r[2] * sc, x2 = r[3] * sc, y2 = r[4] * sc;
            float bw = fmaxf(x2 - x1, 1.0f) * (1.0f / 7.0f);
            float bh = fmaxf(y2 - y1, 1.0f) * (1.0f / 7.0f);
            const float* f = feats[lvl] + (size_t)c * H * H;
            float acc = 0.0f;
#pragma unroll
            for (int sy = 0; sy < 2; ++sy) {
#pragma unroll
                for (int sx = 0; sx < 2; ++sx) {
                    float yc = y1 + ((float)by + 0.25f + 0.5f * sy) * bh;
                    float xc = x1 + ((float)bx + 0.25f + 0.5f * sx) * bw;
                    int4 ey = make_entry_f(yc, H, H);
                    int4 ex = make_entry_f(xc, H, 1);
                    float wyl = __int_as_float(ey.z), wyh = __int_as_float(ey.w);
                    float wxl = __int_as_float(ex.z), wxh = __int_as_float(ex.w);
                    acc += f[ey.x + ex.x] * wyl * wxl + f[ey.x + ex.y] * wyl * wxh +
                           f[ey.y + ex.x] * wyh * wxl + f[ey.y + ex.y] * wyh * wxh;
                }
            }
            m = fmaxf(m, acc * 0.25f);
        }
        out[((size_t)n * NCH + c) * NBIN + b] = m;
    }
}

extern "C" void kernel_launch(void* const* d_in, const int* in_sizes, int n_in, void* d_out,
                              int out_size, void* d_ws, size_t ws_size, hipStream_t stream) {
    const float* f0 = (const float*)d_in[0];
    const float* f1 = (const float*)d_in[1];
    const float* f2 = (const float*)d_in[2];
    const float* f3 = (const float*)d_in[3];
    const float* rois = (const float*)d_in[4];
    int nrois = in_sizes[4] / 5;
    float* out = (float*)d_out;

    const size_t need = 44564480;  // 4 levels NHWC f16
    if (ws_size < need) {
        roi_direct<<<nrois, 256, 0, stream>>>(f0, f1, f2, f3, rois, out);
        return;
    }
    unsigned short* wsp = (unsigned short*)d_ws;

    // cooperative path: size grid to co-resident capacity
    int bpc = 0;
    hipError_t e1 = hipOccupancyMaxActiveBlocksPerMultiprocessor(&bpc, roi_mega, 256, 0);
    int dev = 0, ncu = 0;
    hipGetDevice(&dev);
    hipError_t e2 = hipDeviceGetAttribute(&ncu, hipDeviceAttributeMultiprocessorCount, dev);
    if (e1 == hipSuccess && e2 == hipSuccess && bpc > 0 && ncu > 0) {
        int grid = bpc * ncu;
        if (grid > 4096) grid = 4096;
        void* args[] = {(void*)&f0, (void*)&f1, (void*)&f2, (void*)&f3,
                        (void*)&rois, (void*)&out, (void*)&wsp, (void*)&nrois};
        hipError_t le = hipLaunchCooperativeKernel(roi_mega, dim3(grid), dim3(256), args, 0, stream);
        if (le == hipSuccess) return;
    }
    // split fallback
    transpose_k<<<NTILE, 256, 0, stream>>>(f0, f1, f2, f3, wsp);
    roi_k<<<4 * nrois, 256, 0, stream>>>((const uint4*)d_ws, rois, out, nrois);
}

// Round 5
// 215.218 us; speedup vs baseline: 1.8038x; 1.8038x over previous
//
#include <hip/hip_runtime.h>

// ---------------------------------------------------------------------------
// PASingleRoIExtractor: RoIAlign(out=7, sn=2) on 4 FPN levels + max-combine.
//   1) transpose_flat: NCHW fp32 -> NHWC f16 as a FLAT [C,HW]->[HW,C]
//      transpose (NCHW rows are contiguous, so no y/x math). Register-only,
//      no LDS, no barriers: 8x dwordx4 loads, cvt_pkrtz, 4x dwordx4 stores.
//   2) roi_main4: unchanged from round 3 (4 blocks/roi, 64 ch each,
//      v_dot2_f32_f16 inner loop). Measured 92 us.
//   3) roi_direct fallback if ws too small.
// ---------------------------------------------------------------------------

#define NCH 256
#define NBIN 49

typedef _Float16 half2v __attribute__((ext_vector_type(2)));

#if defined(__has_builtin)
#if __has_builtin(__builtin_amdgcn_fdot2)
#define HAVE_FDOT2 1
#endif
#if __has_builtin(__builtin_amdgcn_cvt_pkrtz)
#define HAVE_PKRTZ 1
#endif
#endif

__device__ __constant__ int    d_H[4]      = {256, 128, 64, 32};
__device__ __constant__ float  d_scale[4]  = {0.25f, 0.125f, 0.0625f, 0.03125f};
__device__ __constant__ int    d_off4[4]   = {0, 2097152, 2621440, 2752512};    // uint4 units
__device__ __constant__ size_t d_offu[4]   = {0, 16777216, 20971520, 22020096}; // f16 units
// flat-transpose tables: P = H*H, blocks of 128 pixels, 4 channel groups
__device__ __constant__ int    d_P[4]      = {65536, 16384, 4096, 1024};
__device__ __constant__ int    d_t2s[4]    = {0, 2048, 2560, 2688};  // block prefix (x4 cg)
__device__ __constant__ int    d_psh[4]    = {9, 7, 5, 3};           // log2(P/128)

__device__ __forceinline__ int pack_h2(float a, float b) {
#ifdef HAVE_PKRTZ
    return __builtin_bit_cast(int, __builtin_amdgcn_cvt_pkrtz(a, b));
#else
    half2v h;
    h.x = (_Float16)a;
    h.y = (_Float16)b;
    return __builtin_bit_cast(int, h);
#endif
}
__device__ __forceinline__ half2v bc_h2(int x) { return __builtin_bit_cast(half2v, x); }
__device__ __forceinline__ half2v bc_h2u(unsigned x) { return __builtin_bit_cast(half2v, x); }

#ifdef HAVE_FDOT2
#define ACC2(uLLc, uLHc, w2, k0)                                                                       \
    acc[k0] = __builtin_amdgcn_fdot2(bc_h2u(__builtin_amdgcn_perm((uLHc), (uLLc), 0x05040100u)), (w2), \
                                     acc[k0], false);                                                  \
    acc[k0 + 1] = __builtin_amdgcn_fdot2(                                                              \
        bc_h2u(__builtin_amdgcn_perm((uLHc), (uLLc), 0x07060302u)), (w2), acc[k0 + 1], false)
#else
#define ACC2(uLLc, uLHc, w2, k0)                                       \
    do {                                                               \
        half2v a_ = bc_h2u(uLLc), b_ = bc_h2u(uLHc);                   \
        float w0_ = (float)(w2).x, w1_ = (float)(w2).y;                \
        acc[k0]     = fmaf((float)a_.x, w0_, acc[k0]);                 \
        acc[k0]     = fmaf((float)b_.x, w1_, acc[k0]);                 \
        acc[k0 + 1] = fmaf((float)a_.y, w0_, acc[k0 + 1]);             \
        acc[k0 + 1] = fmaf((float)b_.y, w1_, acc[k0 + 1]);             \
    } while (0)
#endif

__device__ __forceinline__ void do_sample(const uint4* __restrict__ base, float* acc, int4 ye,
                                          int4 xe) {
    uint4 uLL = base[ye.x + xe.x];
    uint4 uLH = base[ye.x + xe.y];
    uint4 uHL = base[ye.y + xe.x];
    uint4 uHH = base[ye.y + xe.y];
    half2v wx = bc_h2(xe.z);
    half2v wlo = bc_h2(ye.z) * wx;  // {wyl*wxl, wyl*wxh}  (v_pk_mul_f16)
    half2v whi = bc_h2(ye.w) * wx;  // {wyh*wxl, wyh*wxh}
    ACC2(uLL.x, uLH.x, wlo, 0);
    ACC2(uLL.y, uLH.y, wlo, 2);
    ACC2(uLL.z, uLH.z, wlo, 4);
    ACC2(uLL.w, uLH.w, wlo, 6);
    ACC2(uHL.x, uHH.x, whi, 0);
    ACC2(uHL.y, uHH.y, whi, 2);
    ACC2(uHL.z, uHH.z, whi, 4);
    ACC2(uHL.w, uHH.w, whi, 6);
}

// ---------------------------------------------------------------------------
// Flat transpose: [C, P] fp32 -> [P, C] f16 per level. 2720 blocks total.
// Block = 128 flat pixels x 64 channels. Lane = 4 pixels x 8 channels.
// No LDS, no barriers. Loads: 8 dwordx4, 8x128B segs/wave-inst.
// Stores: 4 dwordx4, 8x128B segs/wave-inst.
// ---------------------------------------------------------------------------
__global__ __launch_bounds__(256) void transpose_flat(
    const float* __restrict__ f0, const float* __restrict__ f1, const float* __restrict__ f2,
    const float* __restrict__ f3, unsigned short* __restrict__ out) {
    const int b = blockIdx.x;
    const int lvl = (b >= d_t2s[1]) + (b >= d_t2s[2]) + (b >= d_t2s[3]);
    const int rem = b - d_t2s[lvl];
    const int sh = d_psh[lvl];
    const int pb = rem & ((1 << sh) - 1);  // pixel block
    const int cgi = rem >> sh;             // channel group of 64
    const int P = d_P[lvl];
    const float* in = (lvl == 0) ? f0 : (lvl == 1) ? f1 : (lvl == 2) ? f2 : f3;

    const int tid = threadIdx.x;
    const int o8 = tid & 7;   // channel octet within group
    const int g = tid >> 3;   // pixel quad 0..31
    const int p0 = pb * 128 + g * 4;
    const int c0 = cgi * 64 + o8 * 8;

    const float* src = in + (size_t)c0 * P + p0;
    float vv[32];
#pragma unroll
    for (int r = 0; r < 8; ++r)
        *(float4*)&vv[4 * r] = *(const float4*)(src + (size_t)r * P);

    unsigned short* o = out + d_offu[lvl] + (size_t)p0 * NCH + c0;
#pragma unroll
    for (int j = 0; j < 4; ++j) {
        uint4 d;
        d.x = (unsigned)pack_h2(vv[0 * 4 + j], vv[1 * 4 + j]);
        d.y = (unsigned)pack_h2(vv[2 * 4 + j], vv[3 * 4 + j]);
        d.z = (unsigned)pack_h2(vv[4 * 4 + j], vv[5 * 4 + j]);
        d.w = (unsigned)pack_h2(vv[6 * 4 + j], vv[7 * 4 + j]);
        *(uint4*)(o + (size_t)j * NCH) = d;
    }
}

// ---------------------------------------------------------------------------
// Main roi kernel: FOUR blocks per roi, 64 channels each. (= round 3, 92 us)
// ---------------------------------------------------------------------------
__global__ __launch_bounds__(256) void roi_main4(const uint4* __restrict__ ws,
                                                 const float* __restrict__ rois,
                                                 float* __restrict__ out) {
    __shared__ float smem[64 * NBIN];  // 12544 B
    __shared__ int4 tbl[4][2][14];     // 1792 B

    const int n = blockIdx.x >> 2;
    const int quarter = blockIdx.x & 3;
    const int tid = threadIdx.x;
    const float* r = rois + (size_t)n * 5;

    if (tid < 112) {
        int lvl = tid / 28;
        int e = tid % 28;
        int axis = e / 14;  // 0 = y, 1 = x
        int s = e % 14;
        int H = d_H[lvl];
        float sc = d_scale[lvl];
        float a = (axis ? r[1] : r[2]) * sc;
        float b2 = (axis ? r[3] : r[4]) * sc;
        float binsz = fmaxf(b2 - a, 1.0f) * (1.0f / 7.0f);
        float g = (float)(s >> 1) + 0.25f + 0.5f * (float)(s & 1);
        float coord = a + g * binsz;
        float valid = (coord > -1.0f && coord < (float)H) ? 1.0f : 0.0f;
        float c = fminf(fmaxf(coord, 0.0f), (float)H - 1.0f);
        int lo = (int)floorf(c);
        int hi = min(lo + 1, H - 1);
        float whi = (c - (float)lo) * valid;
        float wlo = (1.0f - (c - (float)lo)) * valid;
        int mult = axis ? 32 : H * 32;  // uint4 units: pixel = 32 uint4
        int4 t;
        t.x = lo * mult;
        t.y = hi * mult;
        if (axis) {
            t.z = pack_h2(wlo, whi);
            t.w = 0;
        } else {
            t.z = pack_h2(wlo, wlo);
            t.w = pack_h2(whi, whi);
        }
        tbl[lvl][axis][s] = t;
    }
    __syncthreads();

    const int p = tid & 7;            // octet within this block's 64 channels
    const int h = tid >> 3;           // 0..31 bin group
    const int octet = quarter * 8 + p;
    const int bstart = (h * NBIN) >> 5;
    const int bend = ((h + 1) * NBIN) >> 5;

    for (int b = bstart; b < bend; ++b) {
        int by = b / 7;
        int bx = b - by * 7;
        float m[8];
#pragma unroll
        for (int k = 0; k < 8; ++k) m[k] = -3.402823e38f;
#pragma unroll
        for (int lvl = 0; lvl < 4; ++lvl) {
            const uint4* base = ws + d_off4[lvl] + octet;
            int4 ye0 = tbl[lvl][0][2 * by];
            int4 ye1 = tbl[lvl][0][2 * by + 1];
            int4 xe0 = tbl[lvl][1][2 * bx];
            int4 xe1 = tbl[lvl][1][2 * bx + 1];
            float acc[8];
#pragma unroll
            for (int k = 0; k < 8; ++k) acc[k] = 0.0f;
            do_sample(base, acc, ye0, xe0);
            do_sample(base, acc, ye0, xe1);
            do_sample(base, acc, ye1, xe0);
            do_sample(base, acc, ye1, xe1);
#pragma unroll
            for (int k = 0; k < 8; ++k) m[k] = fmaxf(m[k], acc[k] * 0.25f);
        }
#pragma unroll
        for (int k = 0; k < 8; ++k) smem[(p * 8 + k) * NBIN + b] = m[k];
    }
    __syncthreads();

    float4* o4 = (float4*)(out + (size_t)n * (NCH * NBIN) + (size_t)quarter * (64 * NBIN));
    const float4* s4 = (const float4*)smem;
    for (int i = tid; i < 64 * NBIN / 4; i += 256) o4[i] = s4[i];
}

// ---------------------------------------------------------------------------
// Fallback: direct NCHW fp32 gather (only if ws too small).
// ---------------------------------------------------------------------------
__device__ __forceinline__ int4 make_entry_f(float coord, int size, int mult) {
    float valid = (coord > -1.0f && coord < (float)size) ? 1.0f : 0.0f;
    float c = fminf(fmaxf(coord, 0.0f), (float)size - 1.0f);
    int lo = (int)floorf(c);
    int hi = min(lo + 1, size - 1);
    float whi = (c - (float)lo) * valid;
    float wlo = (1.0f - (c - (float)lo)) * valid;
    int4 r;
    r.x = lo * mult;
    r.y = hi * mult;
    r.z = __float_as_int(wlo);
    r.w = __float_as_int(whi);
    return r;
}

__global__ __launch_bounds__(256) void roi_direct(
    const float* __restrict__ f0, const float* __restrict__ f1, const float* __restrict__ f2,
    const float* __restrict__ f3, const float* __restrict__ rois, float* __restrict__ out) {
    const int n = blockIdx.x;
    const int c = threadIdx.x;
    const float* feats[4] = {f0, f1, f2, f3};
    const float* r = rois + (size_t)n * 5;
    for (int b = 0; b < NBIN; ++b) {
        int by = b / 7;
        int bx = b - by * 7;
        float m = -3.402823e38f;
#pragma unroll
        for (int lvl = 0; lvl < 4; ++lvl) {
            int H = d_H[lvl];
            float sc = d_scale[lvl];
            float x1 = r[1] * sc, y1 = r[2] * sc, x2 = r[3] * sc, y2 = r[4] * sc;
            float bw = fmaxf(x2 - x1, 1.0f) * (1.0f / 7.0f);
            float bh = fmaxf(y2 - y1, 1.0f) * (1.0f / 7.0f);
            const float* f = feats[lvl] + (size_t)c * H * H;
            float acc = 0.0f;
#pragma unroll
            for (int sy = 0; sy < 2; ++sy) {
#pragma unroll
                for (int sx = 0; sx < 2; ++sx) {
                    float yc = y1 + ((float)by + 0.25f + 0.5f * sy) * bh;
                    float xc = x1 + ((float)bx + 0.25f + 0.5f * sx) * bw;
                    int4 ey = make_entry_f(yc, H, H);
                    int4 ex = make_entry_f(xc, H, 1);
                    float wyl = __int_as_float(ey.z), wyh = __int_as_float(ey.w);
                    float wxl = __int_as_float(ex.z), wxh = __int_as_float(ex.w);
                    acc += f[ey.x + ex.x] * wyl * wxl + f[ey.x + ex.y] * wyl * wxh +
                           f[ey.y + ex.x] * wyh * wxl + f[ey.y + ex.y] * wyh * wxh;
                }
            }
            m = fmaxf(m, acc * 0.25f);
        }
        out[((size_t)n * NCH + c) * NBIN + b] = m;
    }
}

extern "C" void kernel_launch(void* const* d_in, const int* in_sizes, int n_in, void* d_out,
                              int out_size, void* d_ws, size_t ws_size, hipStream_t stream) {
    const float* f0 = (const float*)d_in[0];
    const float* f1 = (const float*)d_in[1];
    const float* f2 = (const float*)d_in[2];
    const float* f3 = (const float*)d_in[3];
    const float* rois = (const float*)d_in[4];
    const int nrois = in_sizes[4] / 5;
    float* out = (float*)d_out;

    const size_t need = 44564480;  // 4 levels NHWC f16
    if (ws_size < need) {
        roi_direct<<<nrois, 256, 0, stream>>>(f0, f1, f2, f3, rois, out);
        return;
    }
    unsigned short* wsp = (unsigned short*)d_ws;
    transpose_flat<<<2720, 256, 0, stream>>>(f0, f1, f2, f3, wsp);
    roi_main4<<<4 * nrois, 256, 0, stream>>>((const uint4*)d_ws, rois, out);
}

// Round 6
// 204.154 us; speedup vs baseline: 1.9016x; 1.0542x over previous
//
#include <hip/hip_runtime.h>

// ---------------------------------------------------------------------------
// PASingleRoIExtractor: RoIAlign(out=7, sn=2) on 4 FPN levels + max-combine.
//   1) transpose_flat: NCHW fp32 -> NHWC f16 flat [C,HW]->[HW,C] transpose.
//      Register-only, no LDS/barriers. (unchanged from round 5)
//   2) roi_main4b: 4 blocks/roi, 64 ch. NEW: 16-load register batching per
//      (bin,level) for 4x MLP; wave-uniform bin passes (b=h, b=h+32).
//   3) roi_direct fallback if ws too small.
// ---------------------------------------------------------------------------

#define NCH 256
#define NBIN 49

typedef _Float16 half2v __attribute__((ext_vector_type(2)));

#if defined(__has_builtin)
#if __has_builtin(__builtin_amdgcn_fdot2)
#define HAVE_FDOT2 1
#endif
#if __has_builtin(__builtin_amdgcn_cvt_pkrtz)
#define HAVE_PKRTZ 1
#endif
#endif

__device__ __constant__ int    d_H[4]      = {256, 128, 64, 32};
__device__ __constant__ float  d_scale[4]  = {0.25f, 0.125f, 0.0625f, 0.03125f};
__device__ __constant__ int    d_off4[4]   = {0, 2097152, 2621440, 2752512};    // uint4 units
__device__ __constant__ size_t d_offu[4]   = {0, 16777216, 20971520, 22020096}; // f16 units
// flat-transpose tables: P = H*H, blocks of 128 pixels, 4 channel groups
__device__ __constant__ int    d_P[4]      = {65536, 16384, 4096, 1024};
__device__ __constant__ int    d_t2s[4]    = {0, 2048, 2560, 2688};  // block prefix (x4 cg)
__device__ __constant__ int    d_psh[4]    = {9, 7, 5, 3};           // log2(P/128)

__device__ __forceinline__ int pack_h2(float a, float b) {
#ifdef HAVE_PKRTZ
    return __builtin_bit_cast(int, __builtin_amdgcn_cvt_pkrtz(a, b));
#else
    half2v h;
    h.x = (_Float16)a;
    h.y = (_Float16)b;
    return __builtin_bit_cast(int, h);
#endif
}
__device__ __forceinline__ half2v bc_h2(int x) { return __builtin_bit_cast(half2v, x); }
__device__ __forceinline__ half2v bc_h2u(unsigned x) { return __builtin_bit_cast(half2v, x); }

#ifdef HAVE_FDOT2
#define ACC2(uLLc, uLHc, w2, k0)                                                                       \
    acc[k0] = __builtin_amdgcn_fdot2(bc_h2u(__builtin_amdgcn_perm((uLHc), (uLLc), 0x05040100u)), (w2), \
                                     acc[k0], false);                                                  \
    acc[k0 + 1] = __builtin_amdgcn_fdot2(                                                              \
        bc_h2u(__builtin_amdgcn_perm((uLHc), (uLLc), 0x07060302u)), (w2), acc[k0 + 1], false)
#else
#define ACC2(uLLc, uLHc, w2, k0)                                       \
    do {                                                               \
        half2v a_ = bc_h2u(uLLc), b_ = bc_h2u(uLHc);                   \
        float w0_ = (float)(w2).x, w1_ = (float)(w2).y;                \
        acc[k0]     = fmaf((float)a_.x, w0_, acc[k0]);                 \
        acc[k0]     = fmaf((float)b_.x, w1_, acc[k0]);                 \
        acc[k0 + 1] = fmaf((float)a_.y, w0_, acc[k0 + 1]);             \
        acc[k0 + 1] = fmaf((float)b_.y, w1_, acc[k0 + 1]);             \
    } while (0)
#endif

// math for one sample: corners LL,LH,HL,HH in L[0..3], weights from (ye,xe)
__device__ __forceinline__ void math4(float* acc, const uint4* L, int4 ye, int4 xe) {
    half2v wx = bc_h2(xe.z);
    half2v wlo = bc_h2(ye.z) * wx;  // {wyl*wxl, wyl*wxh}  (v_pk_mul_f16)
    half2v whi = bc_h2(ye.w) * wx;  // {wyh*wxl, wyh*wxh}
    ACC2(L[0].x, L[1].x, wlo, 0);
    ACC2(L[0].y, L[1].y, wlo, 2);
    ACC2(L[0].z, L[1].z, wlo, 4);
    ACC2(L[0].w, L[1].w, wlo, 6);
    ACC2(L[2].x, L[3].x, whi, 0);
    ACC2(L[2].y, L[3].y, whi, 2);
    ACC2(L[2].z, L[3].z, whi, 4);
    ACC2(L[2].w, L[3].w, whi, 6);
}

// ---------------------------------------------------------------------------
// Flat transpose: [C, P] fp32 -> [P, C] f16 per level. 2720 blocks total.
// ---------------------------------------------------------------------------
__global__ __launch_bounds__(256) void transpose_flat(
    const float* __restrict__ f0, const float* __restrict__ f1, const float* __restrict__ f2,
    const float* __restrict__ f3, unsigned short* __restrict__ out) {
    const int b = blockIdx.x;
    const int lvl = (b >= d_t2s[1]) + (b >= d_t2s[2]) + (b >= d_t2s[3]);
    const int rem = b - d_t2s[lvl];
    const int sh = d_psh[lvl];
    const int pb = rem & ((1 << sh) - 1);  // pixel block
    const int cgi = rem >> sh;             // channel group of 64
    const int P = d_P[lvl];
    const float* in = (lvl == 0) ? f0 : (lvl == 1) ? f1 : (lvl == 2) ? f2 : f3;

    const int tid = threadIdx.x;
    const int o8 = tid & 7;   // channel octet within group
    const int g = tid >> 3;   // pixel quad 0..31
    const int p0 = pb * 128 + g * 4;
    const int c0 = cgi * 64 + o8 * 8;

    const float* src = in + (size_t)c0 * P + p0;
    float vv[32];
#pragma unroll
    for (int r = 0; r < 8; ++r)
        *(float4*)&vv[4 * r] = *(const float4*)(src + (size_t)r * P);

    unsigned short* o = out + d_offu[lvl] + (size_t)p0 * NCH + c0;
#pragma unroll
    for (int j = 0; j < 4; ++j) {
        uint4 d;
        d.x = (unsigned)pack_h2(vv[0 * 4 + j], vv[1 * 4 + j]);
        d.y = (unsigned)pack_h2(vv[2 * 4 + j], vv[3 * 4 + j]);
        d.z = (unsigned)pack_h2(vv[4 * 4 + j], vv[5 * 4 + j]);
        d.w = (unsigned)pack_h2(vv[6 * 4 + j], vv[7 * 4 + j]);
        *(uint4*)(o + (size_t)j * NCH) = d;
    }
}

// ---------------------------------------------------------------------------
// Main roi kernel: 4 blocks/roi, 64 ch each. 16-load batches, 2 bin passes.
// ---------------------------------------------------------------------------
__global__ __launch_bounds__(256) void roi_main4b(const uint4* __restrict__ ws,
                                                  const float* __restrict__ rois,
                                                  float* __restrict__ out) {
    __shared__ float smem[64 * NBIN];  // 12544 B
    __shared__ int4 tbl[4][2][14];     // 1792 B

    const int n = blockIdx.x >> 2;
    const int quarter = blockIdx.x & 3;
    const int tid = threadIdx.x;
    const float* r = rois + (size_t)n * 5;

    if (tid < 112) {
        int lvl = tid / 28;
        int e = tid % 28;
        int axis = e / 14;  // 0 = y, 1 = x
        int s = e % 14;
        int H = d_H[lvl];
        float sc = d_scale[lvl];
        float a = (axis ? r[1] : r[2]) * sc;
        float b2 = (axis ? r[3] : r[4]) * sc;
        float binsz = fmaxf(b2 - a, 1.0f) * (1.0f / 7.0f);
        float g = (float)(s >> 1) + 0.25f + 0.5f * (float)(s & 1);
        float coord = a + g * binsz;
        float valid = (coord > -1.0f && coord < (float)H) ? 1.0f : 0.0f;
        float c = fminf(fmaxf(coord, 0.0f), (float)H - 1.0f);
        int lo = (int)floorf(c);
        int hi = min(lo + 1, H - 1);
        float whi = (c - (float)lo) * valid;
        float wlo = (1.0f - (c - (float)lo)) * valid;
        int mult = axis ? 32 : H * 32;  // uint4 units: pixel = 32 uint4
        int4 t;
        t.x = lo * mult;
        t.y = hi * mult;
        if (axis) {
            t.z = pack_h2(wlo, whi);
            t.w = 0;
        } else {
            t.z = pack_h2(wlo, wlo);
            t.w = pack_h2(whi, whi);
        }
        tbl[lvl][axis][s] = t;
    }
    __syncthreads();

    const int p = tid & 7;   // octet within this block's 64 channels
    const int h = tid >> 3;  // 0..31
    const int octet = quarter * 8 + p;

    // two wave-uniform bin passes: b = h, then b = h + 32
#pragma unroll
    for (int pass = 0; pass < 2; ++pass) {
        const int b = h + pass * 32;
        if (b < NBIN) {
            int by = b / 7;
            int bx = b - by * 7;
            float m[8];
#pragma unroll
            for (int k = 0; k < 8; ++k) m[k] = -3.402823e38f;
#pragma unroll
            for (int lvl = 0; lvl < 4; ++lvl) {
                const uint4* __restrict__ base = ws + d_off4[lvl] + octet;
                int4 ye0 = tbl[lvl][0][2 * by];
                int4 ye1 = tbl[lvl][0][2 * by + 1];
                int4 xe0 = tbl[lvl][1][2 * bx];
                int4 xe1 = tbl[lvl][1][2 * bx + 1];
                // ---- batch all 16 corner loads (4 samples x 4 corners) ----
                uint4 L[16];
                L[0]  = base[ye0.x + xe0.x];
                L[1]  = base[ye0.x + xe0.y];
                L[2]  = base[ye0.y + xe0.x];
                L[3]  = base[ye0.y + xe0.y];
                L[4]  = base[ye0.x + xe1.x];
                L[5]  = base[ye0.x + xe1.y];
                L[6]  = base[ye0.y + xe1.x];
                L[7]  = base[ye0.y + xe1.y];
                L[8]  = base[ye1.x + xe0.x];
                L[9]  = base[ye1.x + xe0.y];
                L[10] = base[ye1.y + xe0.x];
                L[11] = base[ye1.y + xe0.y];
                L[12] = base[ye1.x + xe1.x];
                L[13] = base[ye1.x + xe1.y];
                L[14] = base[ye1.y + xe1.x];
                L[15] = base[ye1.y + xe1.y];
                // ---- then all the math ----
                float acc[8];
#pragma unroll
                for (int k = 0; k < 8; ++k) acc[k] = 0.0f;
                math4(acc, &L[0], ye0, xe0);
                math4(acc, &L[4], ye0, xe1);
                math4(acc, &L[8], ye1, xe0);
                math4(acc, &L[12], ye1, xe1);
#pragma unroll
                for (int k = 0; k < 8; ++k) m[k] = fmaxf(m[k], acc[k] * 0.25f);
            }
#pragma unroll
            for (int k = 0; k < 8; ++k) smem[(p * 8 + k) * NBIN + b] = m[k];
        }
    }
    __syncthreads();

    float4* o4 = (float4*)(out + (size_t)n * (NCH * NBIN) + (size_t)quarter * (64 * NBIN));
    const float4* s4 = (const float4*)smem;
    for (int i = tid; i < 64 * NBIN / 4; i += 256) o4[i] = s4[i];
}

// ---------------------------------------------------------------------------
// Fallback: direct NCHW fp32 gather (only if ws too small).
// ---------------------------------------------------------------------------
__device__ __forceinline__ int4 make_entry_f(float coord, int size, int mult) {
    float valid = (coord > -1.0f && coord < (float)size) ? 1.0f : 0.0f;
    float c = fminf(fmaxf(coord, 0.0f), (float)size - 1.0f);
    int lo = (int)floorf(c);
    int hi = min(lo + 1, size - 1);
    float whi = (c - (float)lo) * valid;
    float wlo = (1.0f - (c - (float)lo)) * valid;
    int4 r;
    r.x = lo * mult;
    r.y = hi * mult;
    r.z = __float_as_int(wlo);
    r.w = __float_as_int(whi);
    return r;
}

__global__ __launch_bounds__(256) void roi_direct(
    const float* __restrict__ f0, const float* __restrict__ f1, const float* __restrict__ f2,
    const float* __restrict__ f3, const float* __restrict__ rois, float* __restrict__ out) {
    const int n = blockIdx.x;
    const int c = threadIdx.x;
    const float* feats[4] = {f0, f1, f2, f3};
    const float* r = rois + (size_t)n * 5;
    for (int b = 0; b < NBIN; ++b) {
        int by = b / 7;
        int bx = b - by * 7;
        float m = -3.402823e38f;
#pragma unroll
        for (int lvl = 0; lvl < 4; ++lvl) {
            int H = d_H[lvl];
            float sc = d_scale[lvl];
            float x1 = r[1] * sc, y1 = r[2] * sc, x2 = r[3] * sc, y2 = r[4] * sc;
            float bw = fmaxf(x2 - x1, 1.0f) * (1.0f / 7.0f);
            float bh = fmaxf(y2 - y1, 1.0f) * (1.0f / 7.0f);
            const float* f = feats[lvl] + (size_t)c * H * H;
            float acc = 0.0f;
#pragma unroll
            for (int sy = 0; sy < 2; ++sy) {
#pragma unroll
                for (int sx = 0; sx < 2; ++sx) {
                    float yc = y1 + ((float)by + 0.25f + 0.5f * sy) * bh;
                    float xc = x1 + ((float)bx + 0.25f + 0.5f * sx) * bw;
                    int4 ey = make_entry_f(yc, H, H);
                    int4 ex = make_entry_f(xc, H, 1);
                    float wyl = __int_as_float(ey.z), wyh = __int_as_float(ey.w);
                    float wxl = __int_as_float(ex.z), wxh = __int_as_float(ex.w);
                    acc += f[ey.x + ex.x] * wyl * wxl + f[ey.x + ex.y] * wyl * wxh +
                           f[ey.y + ex.x] * wyh * wxl + f[ey.y + ex.y] * wyh * wxh;
                }
            }
            m = fmaxf(m, acc * 0.25f);
        }
        out[((size_t)n * NCH + c) * NBIN + b] = m;
    }
}

extern "C" void kernel_launch(void* const* d_in, const int* in_sizes, int n_in, void* d_out,
                              int out_size, void* d_ws, size_t ws_size, hipStream_t stream) {
    const float* f0 = (const float*)d_in[0];
    const float* f1 = (const float*)d_in[1];
    const float* f2 = (const float*)d_in[2];
    const float* f3 = (const float*)d_in[3];
    const float* rois = (const float*)d_in[4];
    const int nrois = in_sizes[4] / 5;
    float* out = (float*)d_out;

    const size_t need = 44564480;  // 4 levels NHWC f16
    if (ws_size < need) {
        roi_direct<<<nrois, 256, 0, stream>>>(f0, f1, f2, f3, rois, out);
        return;
    }
    unsigned short* wsp = (unsigned short*)d_ws;
    transpose_flat<<<2720, 256, 0, stream>>>(f0, f1, f2, f3, wsp);
    roi_main4b<<<4 * nrois, 256, 0, stream>>>((const uint4*)d_ws, rois, out);
}